// Round 1
// baseline (174.533 us; speedup 1.0000x reference)
//
#include <hip/hip_runtime.h>
#include <cstdint>
#include <cstddef>

typedef unsigned short u16;

#define S_LEN 4096
#define H_N 8
#define D_N 64

__device__ __forceinline__ float bf2f(u16 u) {
  return __uint_as_float(((unsigned int)u) << 16);
}
__device__ __forceinline__ u16 f2bf(float f) {
  unsigned int x = __float_as_uint(f);
  return (u16)((x + 0x7fffu + ((x >> 16) & 1u)) >> 16);
}

__device__ __forceinline__ void fma16(float acc[4][4], float w0, float w1,
                                      float w2, float w3, float4 xv) {
  acc[0][0] += w0 * xv.x; acc[0][1] += w0 * xv.y; acc[0][2] += w0 * xv.z; acc[0][3] += w0 * xv.w;
  acc[1][0] += w1 * xv.x; acc[1][1] += w1 * xv.y; acc[1][2] += w1 * xv.z; acc[1][3] += w1 * xv.w;
  acc[2][0] += w2 * xv.x; acc[2][1] += w2 * xv.y; acc[2][2] += w2 * xv.z; acc[2][3] += w2 * xv.w;
  acc[3][0] += w3 * xv.x; acc[3][1] += w3 * xv.y; acc[3][2] += w3 * xv.z; acc[3][3] += w3 * xv.w;
}

// ---------------------------------------------------------------------------
// stepA from q (fp32, layout [B,S,H,D]):
//   T[bh][m][j][d] = sum_k W[m][j][k] * q[b, k*64+m, h, d]
// grid: (m=64, bh=64), block 256
// ---------------------------------------------------------------------------
__global__ __launch_bounds__(256) void k_stepA_q(const float* __restrict__ q,
                                                 const float* __restrict__ W,
                                                 u16* __restrict__ T) {
  const int m = blockIdx.x, bh = blockIdx.y;
  const int b = bh >> 3, h = bh & 7;
  __shared__ float Xs[64][64];   // [k][d]
  __shared__ float Wt[64][65];   // [k][j], padded
  const int tid = threadIdx.x;
#pragma unroll
  for (int it = 0; it < 4; ++it) {
    int c = tid + it * 256;
    int kk = c >> 4, d4 = (c & 15) * 4;
    const float4 vv = *reinterpret_cast<const float4*>(
        &q[(((size_t)b * S_LEN + (size_t)kk * 64 + m) * H_N + h) * D_N + d4]);
    Xs[kk][d4] = vv.x; Xs[kk][d4 + 1] = vv.y; Xs[kk][d4 + 2] = vv.z; Xs[kk][d4 + 3] = vv.w;
  }
#pragma unroll
  for (int it = 0; it < 4; ++it) {
    int c = tid + it * 256;
    int j = c >> 4, k4 = (c & 15) * 4;
    const float4 vv = *reinterpret_cast<const float4*>(&W[((size_t)m * 64 + j) * 64 + k4]);
    Wt[k4][j] = vv.x; Wt[k4 + 1][j] = vv.y; Wt[k4 + 2][j] = vv.z; Wt[k4 + 3][j] = vv.w;
  }
  __syncthreads();
  const int j0 = (tid >> 4) * 4, d0 = (tid & 15) * 4;
  float acc[4][4] = {};
#pragma unroll 4
  for (int kk = 0; kk < 64; ++kk) {
    float4 xv = *reinterpret_cast<const float4*>(&Xs[kk][d0]);
    fma16(acc, Wt[kk][j0], Wt[kk][j0 + 1], Wt[kk][j0 + 2], Wt[kk][j0 + 3], xv);
  }
#pragma unroll
  for (int a = 0; a < 4; ++a) {
    ushort4 o;
    o.x = f2bf(acc[a][0]); o.y = f2bf(acc[a][1]); o.z = f2bf(acc[a][2]); o.w = f2bf(acc[a][3]);
    *reinterpret_cast<ushort4*>(&T[(((size_t)bh * 64 + m) * 64 + (j0 + a)) * 64 + d0]) = o;
  }
}

// ---------------------------------------------------------------------------
// stepA from A (bf16, layout [bh][s][d]):
//   T[bh][m][j][d] = sum_k W[m][j][k] * A[bh][k*64+m][d]
// ---------------------------------------------------------------------------
__global__ __launch_bounds__(256) void k_stepA_u(const u16* __restrict__ A,
                                                 const float* __restrict__ W,
                                                 u16* __restrict__ T) {
  const int m = blockIdx.x, bh = blockIdx.y;
  __shared__ float Xs[64][64];
  __shared__ float Wt[64][65];
  const int tid = threadIdx.x;
#pragma unroll
  for (int it = 0; it < 4; ++it) {
    int c = tid + it * 256;
    int kk = c >> 4, d4 = (c & 15) * 4;
    ushort4 t = *reinterpret_cast<const ushort4*>(
        &A[((size_t)bh * S_LEN + (size_t)kk * 64 + m) * D_N + d4]);
    Xs[kk][d4] = bf2f(t.x); Xs[kk][d4 + 1] = bf2f(t.y);
    Xs[kk][d4 + 2] = bf2f(t.z); Xs[kk][d4 + 3] = bf2f(t.w);
  }
#pragma unroll
  for (int it = 0; it < 4; ++it) {
    int c = tid + it * 256;
    int j = c >> 4, k4 = (c & 15) * 4;
    const float4 vv = *reinterpret_cast<const float4*>(&W[((size_t)m * 64 + j) * 64 + k4]);
    Wt[k4][j] = vv.x; Wt[k4 + 1][j] = vv.y; Wt[k4 + 2][j] = vv.z; Wt[k4 + 3][j] = vv.w;
  }
  __syncthreads();
  const int j0 = (tid >> 4) * 4, d0 = (tid & 15) * 4;
  float acc[4][4] = {};
#pragma unroll 4
  for (int kk = 0; kk < 64; ++kk) {
    float4 xv = *reinterpret_cast<const float4*>(&Xs[kk][d0]);
    fma16(acc, Wt[kk][j0], Wt[kk][j0 + 1], Wt[kk][j0 + 2], Wt[kk][j0 + 3], xv);
  }
#pragma unroll
  for (int a = 0; a < 4; ++a) {
    ushort4 o;
    o.x = f2bf(acc[a][0]); o.y = f2bf(acc[a][1]); o.z = f2bf(acc[a][2]); o.w = f2bf(acc[a][3]);
    *reinterpret_cast<ushort4*>(&T[(((size_t)bh * 64 + m) * 64 + (j0 + a)) * 64 + d0]) = o;
  }
}

// ---------------------------------------------------------------------------
// stepB1: A[bh][s][d] = (sum_m R[j][i][m] * T[bh][m][j][d]) * keys[b,s,h,d] + b1[s]
//   with s = i*64 + j.  grid: (j=64, bh=64)
// ---------------------------------------------------------------------------
__global__ __launch_bounds__(256) void k_stepB1(const u16* __restrict__ T,
                                                const float* __restrict__ Rw,
                                                const float* __restrict__ keys,
                                                const float* __restrict__ b1,
                                                u16* __restrict__ A) {
  const int j = blockIdx.x, bh = blockIdx.y;
  const int b = bh >> 3, h = bh & 7;
  __shared__ float Ts[64][64];   // [m][d]
  __shared__ float Rt[64][65];   // [m][i], padded
  const int tid = threadIdx.x;
#pragma unroll
  for (int it = 0; it < 4; ++it) {
    int c = tid + it * 256;
    int mm = c >> 4, d4 = (c & 15) * 4;
    ushort4 t = *reinterpret_cast<const ushort4*>(
        &T[(((size_t)bh * 64 + mm) * 64 + j) * 64 + d4]);
    Ts[mm][d4] = bf2f(t.x); Ts[mm][d4 + 1] = bf2f(t.y);
    Ts[mm][d4 + 2] = bf2f(t.z); Ts[mm][d4 + 3] = bf2f(t.w);
  }
#pragma unroll
  for (int it = 0; it < 4; ++it) {
    int c = tid + it * 256;
    int i = c >> 4, m4 = (c & 15) * 4;
    const float4 vv = *reinterpret_cast<const float4*>(&Rw[((size_t)j * 64 + i) * 64 + m4]);
    Rt[m4][i] = vv.x; Rt[m4 + 1][i] = vv.y; Rt[m4 + 2][i] = vv.z; Rt[m4 + 3][i] = vv.w;
  }
  __syncthreads();
  const int i0 = (tid >> 4) * 4, d0 = (tid & 15) * 4;
  float acc[4][4] = {};
#pragma unroll 4
  for (int mm = 0; mm < 64; ++mm) {
    float4 xv = *reinterpret_cast<const float4*>(&Ts[mm][d0]);
    fma16(acc, Rt[mm][i0], Rt[mm][i0 + 1], Rt[mm][i0 + 2], Rt[mm][i0 + 3], xv);
  }
#pragma unroll
  for (int a = 0; a < 4; ++a) {
    int i = i0 + a, s = i * 64 + j;
    float bb = b1[s];
    float4 kv = *reinterpret_cast<const float4*>(
        &keys[(((size_t)b * S_LEN + s) * H_N + h) * D_N + d0]);
    ushort4 o;
    o.x = f2bf(acc[a][0] * kv.x + bb);
    o.y = f2bf(acc[a][1] * kv.y + bb);
    o.z = f2bf(acc[a][2] * kv.z + bb);
    o.w = f2bf(acc[a][3] * kv.w + bb);
    *reinterpret_cast<ushort4*>(&A[((size_t)bh * S_LEN + s) * D_N + d0]) = o;
  }
}

// ---------------------------------------------------------------------------
// stepB2: Yp[bh][s][d] = (sum_m R[j][i][m] * T[bh][m][j][d] + b2[s]) * v[b,s,h,d]
// ---------------------------------------------------------------------------
__global__ __launch_bounds__(256) void k_stepB2(const u16* __restrict__ T,
                                                const float* __restrict__ Rw,
                                                const float* __restrict__ vals,
                                                const float* __restrict__ b2,
                                                u16* __restrict__ Yp) {
  const int j = blockIdx.x, bh = blockIdx.y;
  const int b = bh >> 3, h = bh & 7;
  __shared__ float Ts[64][64];
  __shared__ float Rt[64][65];
  const int tid = threadIdx.x;
#pragma unroll
  for (int it = 0; it < 4; ++it) {
    int c = tid + it * 256;
    int mm = c >> 4, d4 = (c & 15) * 4;
    ushort4 t = *reinterpret_cast<const ushort4*>(
        &T[(((size_t)bh * 64 + mm) * 64 + j) * 64 + d4]);
    Ts[mm][d4] = bf2f(t.x); Ts[mm][d4 + 1] = bf2f(t.y);
    Ts[mm][d4 + 2] = bf2f(t.z); Ts[mm][d4 + 3] = bf2f(t.w);
  }
#pragma unroll
  for (int it = 0; it < 4; ++it) {
    int c = tid + it * 256;
    int i = c >> 4, m4 = (c & 15) * 4;
    const float4 vv = *reinterpret_cast<const float4*>(&Rw[((size_t)j * 64 + i) * 64 + m4]);
    Rt[m4][i] = vv.x; Rt[m4 + 1][i] = vv.y; Rt[m4 + 2][i] = vv.z; Rt[m4 + 3][i] = vv.w;
  }
  __syncthreads();
  const int i0 = (tid >> 4) * 4, d0 = (tid & 15) * 4;
  float acc[4][4] = {};
#pragma unroll 4
  for (int mm = 0; mm < 64; ++mm) {
    float4 xv = *reinterpret_cast<const float4*>(&Ts[mm][d0]);
    fma16(acc, Rt[mm][i0], Rt[mm][i0 + 1], Rt[mm][i0 + 2], Rt[mm][i0 + 3], xv);
  }
#pragma unroll
  for (int a = 0; a < 4; ++a) {
    int i = i0 + a, s = i * 64 + j;
    float bb = b2[s];
    float4 vv = *reinterpret_cast<const float4*>(
        &vals[(((size_t)b * S_LEN + s) * H_N + h) * D_N + d0]);
    ushort4 o;
    o.x = f2bf((acc[a][0] + bb) * vv.x);
    o.y = f2bf((acc[a][1] + bb) * vv.y);
    o.z = f2bf((acc[a][2] + bb) * vv.z);
    o.w = f2bf((acc[a][3] + bb) * vv.w);
    *reinterpret_cast<ushort4*>(&Yp[((size_t)bh * S_LEN + s) * D_N + d0]) = o;
  }
}

// ---------------------------------------------------------------------------
// final transpose: out[bh][d][s] = Yp[bh][s][d]   (fp32 output)
// grid: (sblk=64, bh=64)
// ---------------------------------------------------------------------------
__global__ __launch_bounds__(256) void k_out(const u16* __restrict__ Yp,
                                             float* __restrict__ out) {
  const int sblk = blockIdx.x, bh = blockIdx.y;
  __shared__ float Ys[64][65];
  const int tid = threadIdx.x;
#pragma unroll
  for (int it = 0; it < 4; ++it) {
    int c = tid + it * 256;
    int sl = c >> 4, d4 = (c & 15) * 4;
    ushort4 t = *reinterpret_cast<const ushort4*>(
        &Yp[((size_t)bh * S_LEN + (size_t)sblk * 64 + sl) * D_N + d4]);
    Ys[sl][d4] = bf2f(t.x); Ys[sl][d4 + 1] = bf2f(t.y);
    Ys[sl][d4 + 2] = bf2f(t.z); Ys[sl][d4 + 3] = bf2f(t.w);
  }
  __syncthreads();
#pragma unroll
  for (int it = 0; it < 4; ++it) {
    int c = tid + it * 256;
    int d = c >> 4, sl4 = (c & 15) * 4;
    float4 o;
    o.x = Ys[sl4][d]; o.y = Ys[sl4 + 1][d]; o.z = Ys[sl4 + 2][d]; o.w = Ys[sl4 + 3][d];
    *reinterpret_cast<float4*>(
        &out[((size_t)bh * 64 + d) * S_LEN + (size_t)sblk * 64 + sl4]) = o;
  }
}

// ---------------------------------------------------------------------------
extern "C" void kernel_launch(void* const* d_in, const int* in_sizes, int n_in,
                              void* d_out, int out_size, void* d_ws, size_t ws_size,
                              hipStream_t stream) {
  const float* q   = (const float*)d_in[0];
  const float* k   = (const float*)d_in[1];
  const float* v   = (const float*)d_in[2];
  const float* M1L = (const float*)d_in[3];
  const float* M1R = (const float*)d_in[4];
  const float* M2L = (const float*)d_in[5];
  const float* M2R = (const float*)d_in[6];
  const float* b1  = (const float*)d_in[7];
  const float* b2  = (const float*)d_in[8];
  float* out = (float*)d_out;

  // workspace: two bf16 buffers of 64*4096*64 = 16,777,216 elements each (32 MB each)
  u16* Tbuf = (u16*)d_ws;
  u16* Ubuf = Tbuf + (size_t)64 * S_LEN * D_N;

  dim3 blk(256);
  dim3 grd(64, 64);   // (m or j or sblk, bh)

  k_stepA_q<<<grd, blk, 0, stream>>>(q, M1L, Tbuf);          // T1
  k_stepB1 <<<grd, blk, 0, stream>>>(Tbuf, M1R, k, b1, Ubuf); // A
  k_stepA_u<<<grd, blk, 0, stream>>>(Ubuf, M2L, Tbuf);        // T2
  k_stepB2 <<<grd, blk, 0, stream>>>(Tbuf, M2R, v, b2, Ubuf); // Yp
  k_out    <<<grd, blk, 0, stream>>>(Ubuf, out);              // Y
}

// Round 2
// 135.452 us; speedup vs baseline: 1.2885x; 1.2885x over previous
//
#include <hip/hip_runtime.h>
#include <cstdint>
#include <cstddef>

typedef unsigned short u16;
typedef __attribute__((ext_vector_type(8))) short bf16x8;
typedef __attribute__((ext_vector_type(4))) float f32x4;

#define S_LEN 4096

__device__ __forceinline__ float bf2f(u16 u) {
  return __uint_as_float(((unsigned)u) << 16);
}
__device__ __forceinline__ u16 f2bf(float f) {
  unsigned x = __float_as_uint(f);
  return (u16)((x + 0x7fffu + ((x >> 16) & 1u)) >> 16);
}

// LDS transposed-activation tile: logical (c=col 0..63, r=row 0..63), row = contraction dim.
// k-innermost runs of 8 for ds_read_b128; XOR swizzle spreads banks for both the
// scalar transpose-writes and the b128 fragment reads.
__device__ __forceinline__ int ltelem(int c, int r) {
  int swz = ((r >> 3) ^ (c & 7) ^ ((c >> 3) & 7)) & 7;
  return (c << 6) | (swz << 3) | (r & 7);
}

// A-fragment from fp32 weight row (row-major, contraction innermost).
// lane row = lane&15 (within the wave's 16-row M slice); 8 k-elems per lane.
__device__ __forceinline__ bf16x8 load_afrag(const float* __restrict__ Wrow, int ks, int lane) {
  const float4* p = (const float4*)(Wrow + ks * 32 + ((lane >> 4) << 3));
  float4 a = p[0], b = p[1];
  bf16x8 r;
  r[0] = (short)f2bf(a.x); r[1] = (short)f2bf(a.y);
  r[2] = (short)f2bf(a.z); r[3] = (short)f2bf(a.w);
  r[4] = (short)f2bf(b.x); r[5] = (short)f2bf(b.y);
  r[6] = (short)f2bf(b.z); r[7] = (short)f2bf(b.w);
  return r;
}

// B-fragment from swizzled LDS tile: col = fc*16 + (lane&15), k-run = (ks*4 + lane>>4)*8.
__device__ __forceinline__ bf16x8 load_bfrag(const ushort* LT, int fc, int ks, int lane) {
  int c = (fc << 4) + (lane & 15);
  int kg = (ks << 2) + (lane >> 4);
  int base = (c << 6) | (((kg ^ (c & 7) ^ ((c >> 3) & 7)) & 7) << 3);
  return *(const bf16x8*)&LT[base];
}

// One wave computes C[16 rows x 64 cols] = A[16 x 64] * B[64 x 64] with bf16 MFMA.
__device__ __forceinline__ void mm16x64(const float* __restrict__ Arow, const ushort* LT,
                                        int lane, f32x4 acc[4]) {
#pragma unroll
  for (int ks = 0; ks < 2; ++ks) {
    bf16x8 af = load_afrag(Arow, ks, lane);
#pragma unroll
    for (int fc = 0; fc < 4; ++fc) {
      bf16x8 bf = load_bfrag(LT, fc, ks, lane);
      acc[fc] = __builtin_amdgcn_mfma_f32_16x16x32_bf16(af, bf, acc[fc], 0, 0, 0);
    }
  }
}

// ---------------------------------------------------------------------------
// K1: T1[bh][n][B][d] = sum_m L1[B][n][m] * q[b, m*64+B, h, d]   (bf16 out)
// grid (B=64, bh=64), 256 thr (4 waves, wave w owns n-slice [16w,16w+16))
// ---------------------------------------------------------------------------
__global__ __launch_bounds__(256) void k_m1(const float* __restrict__ q,
                                            const float* __restrict__ L1,
                                            u16* __restrict__ T1) {
  const int B = blockIdx.x, bh = blockIdx.y;
  const int b = bh >> 3, h = bh & 7;
  __shared__ ushort LT[4096];
  const int tid = threadIdx.x, w = tid >> 6, lane = tid & 63;
  {
    const int m = tid >> 2, ch = tid & 3;
    const float* qrow = q + ((((size_t)b * S_LEN + (size_t)m * 64 + B) * 8 + h) << 6);
#pragma unroll
    for (int i = 0; i < 4; ++i) {
      float4 v = *(const float4*)(qrow + ch * 16 + i * 4);
      int c0 = ch * 16 + i * 4;
      LT[ltelem(c0 + 0, m)] = f2bf(v.x);
      LT[ltelem(c0 + 1, m)] = f2bf(v.y);
      LT[ltelem(c0 + 2, m)] = f2bf(v.z);
      LT[ltelem(c0 + 3, m)] = f2bf(v.w);
    }
  }
  __syncthreads();
  f32x4 acc[4] = {};
  mm16x64(L1 + (((size_t)B << 6) + (w << 4) + (lane & 15)) * 64, LT, lane, acc);
#pragma unroll
  for (int fc = 0; fc < 4; ++fc) {
    int d = (fc << 4) + (lane & 15);
#pragma unroll
    for (int r = 0; r < 4; ++r) {
      int n = (w << 4) + ((lane >> 4) << 2) + r;
      T1[(((size_t)bh * 64 + n) * 64 + B) * 64 + d] = f2bf(acc[fc][r]);
    }
  }
}

// ---------------------------------------------------------------------------
// K2: per (bh, n-octet):  mm(R1) -> *k + b1 -> mm(L2) -> T2[bh][n'][n][d]
// grid (o=8, bh=64)
// ---------------------------------------------------------------------------
__global__ __launch_bounds__(256) void k_m2(const u16* __restrict__ T1,
                                            const float* __restrict__ R1,
                                            const float* __restrict__ L2,
                                            const float* __restrict__ keys,
                                            const float* __restrict__ b1,
                                            u16* __restrict__ T2) {
  const int o = blockIdx.x, bh = blockIdx.y;
  const int b = bh >> 3, h = bh & 7;
  __shared__ ushort LT[4096];
  __shared__ ushort LT2[4096];
  const int tid = threadIdx.x, w = tid >> 6, lane = tid & 63;
  const int rowi = tid >> 2, ch = tid & 3;
  for (int nl = 0; nl < 8; ++nl) {
    const int n = (o << 3) + nl;
    __syncthreads();  // protect LT/LT2 from previous iteration's readers
    {
      const u16* src = T1 + (((size_t)bh * 64 + n) * 64 + rowi) * 64 + ch * 16;
      u16 buf[16];
      *(uint4*)&buf[0] = *(const uint4*)(src);
      *(uint4*)&buf[8] = *(const uint4*)(src + 8);
#pragma unroll
      for (int e = 0; e < 16; ++e) LT[ltelem(ch * 16 + e, rowi)] = buf[e];
    }
    __syncthreads();
    // mm1: rows p (wave slice), contraction B, cols d
    f32x4 acc[4] = {};
    mm16x64(R1 + ((size_t)n * 64 + (w << 4) + (lane & 15)) * 64, LT, lane, acc);
    float b1v[4];
#pragma unroll
    for (int r = 0; r < 4; ++r)
      b1v[r] = b1[((w << 4) + ((lane >> 4) << 2) + r) * 64 + n];
#pragma unroll
    for (int fc = 0; fc < 4; ++fc) {
      int d = (fc << 4) + (lane & 15);
#pragma unroll
      for (int r = 0; r < 4; ++r) {
        int p = (w << 4) + ((lane >> 4) << 2) + r;
        float kv = keys[(((size_t)b * S_LEN + p * 64 + n) * 8 + h) * 64 + d];
        LT2[ltelem(d, p)] = f2bf(acc[fc][r] * kv + b1v[r]);
      }
    }
    __syncthreads();
    // mm2: rows n' (wave slice), contraction m'=p, cols d
    f32x4 acc2[4] = {};
    mm16x64(L2 + ((size_t)n * 64 + (w << 4) + (lane & 15)) * 64, LT2, lane, acc2);
#pragma unroll
    for (int fc = 0; fc < 4; ++fc) {
      int d = (fc << 4) + (lane & 15);
#pragma unroll
      for (int r = 0; r < 4; ++r) {
        int n2 = (w << 4) + ((lane >> 4) << 2) + r;
        T2[(((size_t)bh * 64 + n2) * 64 + n) * 64 + d] = f2bf(acc2[fc][r]);
      }
    }
  }
}

// ---------------------------------------------------------------------------
// K3: per (bh, n'-octet): mm(R2) -> (+b2)*v -> LDS stage -> out[bh][d][s] fp32
// grid (o=8, bh=64).  LDS stage regroups 8 n' per lane so the final stores are
// 32B-contiguous float4 pairs.
// ---------------------------------------------------------------------------
__global__ __launch_bounds__(256) void k_m3(const u16* __restrict__ T2,
                                            const float* __restrict__ R2,
                                            const float* __restrict__ vals,
                                            const float* __restrict__ b2,
                                            float* __restrict__ out) {
  const int o = blockIdx.x, bh = blockIdx.y;
  const int b = bh >> 3, h = bh & 7;
  __shared__ ushort LT[4096];
  __shared__ ushort SG[32768];  // [p][d][n'loc 8] bf16, dword-XOR-swizzled
  const int tid = threadIdx.x, w = tid >> 6, lane = tid & 63;
  const int rowi = tid >> 2, ch = tid & 3;
  for (int nl = 0; nl < 8; ++nl) {
    const int np = (o << 3) + nl;
    __syncthreads();
    {
      const u16* src = T2 + (((size_t)bh * 64 + np) * 64 + rowi) * 64 + ch * 16;
      u16 buf[16];
      *(uint4*)&buf[0] = *(const uint4*)(src);
      *(uint4*)&buf[8] = *(const uint4*)(src + 8);
#pragma unroll
      for (int e = 0; e < 16; ++e) LT[ltelem(ch * 16 + e, rowi)] = buf[e];
    }
    __syncthreads();
    // mm3: rows p' (wave slice), contraction n, cols d
    f32x4 acc[4] = {};
    mm16x64(R2 + ((size_t)np * 64 + (w << 4) + (lane & 15)) * 64, LT, lane, acc);
    float b2v[4];
#pragma unroll
    for (int r = 0; r < 4; ++r)
      b2v[r] = b2[((w << 4) + ((lane >> 4) << 2) + r) * 64 + np];
    int qw = nl >> 1;
#pragma unroll
    for (int fc = 0; fc < 4; ++fc) {
      int d = (fc << 4) + (lane & 15);
      int d43 = (d >> 3) & 3;
#pragma unroll
      for (int r = 0; r < 4; ++r) {
        int p = (w << 4) + ((lane >> 4) << 2) + r;
        float vv = vals[(((size_t)b * S_LEN + p * 64 + np) * 8 + h) * 64 + d];
        float y = (acc[fc][r] + b2v[r]) * vv;
        int g2 = (p >> 2) & 3;
        int pos = (qw ^ g2 ^ d43) & 3;
        SG[(((p << 6) + d) << 3) + pos * 2 + (nl & 1)] = f2bf(y);
      }
    }
  }
  __syncthreads();
#pragma unroll
  for (int it = 0; it < 16; ++it) {
    int cell = it * 256 + tid;
    int d = cell & 63, p = cell >> 6;
    int g2 = (p >> 2) & 3, d43 = (d >> 3) & 3;
    int base = ((p << 6) + d) << 3;
    float o8[8];
#pragma unroll
    for (int qd = 0; qd < 4; ++qd) {
      unsigned vv = *(const unsigned*)&SG[base + ((qd ^ g2 ^ d43) & 3) * 2];
      o8[qd * 2 + 0] = bf2f((u16)(vv & 0xffffu));
      o8[qd * 2 + 1] = bf2f((u16)(vv >> 16));
    }
    float* op = out + ((size_t)bh * 64 + d) * S_LEN + (p << 6) + (o << 3);
    float4 s0 = {o8[0], o8[1], o8[2], o8[3]};
    float4 s1 = {o8[4], o8[5], o8[6], o8[7]};
    *(float4*)op = s0;
    *(float4*)(op + 4) = s1;
  }
}

// ---------------------------------------------------------------------------
extern "C" void kernel_launch(void* const* d_in, const int* in_sizes, int n_in,
                              void* d_out, int out_size, void* d_ws, size_t ws_size,
                              hipStream_t stream) {
  const float* q   = (const float*)d_in[0];
  const float* k   = (const float*)d_in[1];
  const float* v   = (const float*)d_in[2];
  const float* M1L = (const float*)d_in[3];
  const float* M1R = (const float*)d_in[4];
  const float* M2L = (const float*)d_in[5];
  const float* M2R = (const float*)d_in[6];
  const float* b1  = (const float*)d_in[7];
  const float* b2  = (const float*)d_in[8];

  u16* T1 = (u16*)d_ws;
  u16* T2 = T1 + (size_t)64 * 64 * 64 * 64;  // 16,777,216 elems each (32 MB)

  dim3 blk(256);
  k_m1<<<dim3(64, 64), blk, 0, stream>>>(q, M1L, T1);
  k_m2<<<dim3(8, 64), blk, 0, stream>>>(T1, M1R, M2L, k, b1, T2);
  k_m3<<<dim3(8, 64), blk, 0, stream>>>(T2, M2R, v, b2, (float*)d_out);
}

// Round 3
// 116.081 us; speedup vs baseline: 1.5035x; 1.1669x over previous
//
#include <hip/hip_runtime.h>
#include <cstdint>
#include <cstddef>

typedef unsigned short u16;
typedef __attribute__((ext_vector_type(8))) short bf16x8;
typedef __attribute__((ext_vector_type(4))) float f32x4;

#define S_LEN 4096

__device__ __forceinline__ float bf2f(u16 u) {
  return __uint_as_float(((unsigned)u) << 16);
}
__device__ __forceinline__ u16 f2bf(float f) {
  unsigned x = __float_as_uint(f);
  return (u16)((x + 0x7fffu + ((x >> 16) & 1u)) >> 16);
}

// XOR-swizzled 64x64 u16 LDS tile: logical (c=col, r=row). 8-elem runs of r
// stay contiguous (16B) so ds_read/write_b128 works; swizzle spreads banks.
__device__ __forceinline__ int ltelem(int c, int r) {
  int swz = ((r >> 3) ^ (c & 7) ^ ((c >> 3) & 7)) & 7;
  return (c << 6) | (swz << 3) | (r & 7);
}

// A-fragment from fp32 weight row (row-major, contraction innermost).
__device__ __forceinline__ bf16x8 load_afrag(const float* __restrict__ Wrow, int ks, int lane) {
  const float4* p = (const float4*)(Wrow + ks * 32 + ((lane >> 4) << 3));
  float4 a = p[0], b = p[1];
  bf16x8 r;
  r[0] = (short)f2bf(a.x); r[1] = (short)f2bf(a.y);
  r[2] = (short)f2bf(a.z); r[3] = (short)f2bf(a.w);
  r[4] = (short)f2bf(b.x); r[5] = (short)f2bf(b.y);
  r[6] = (short)f2bf(b.z); r[7] = (short)f2bf(b.w);
  return r;
}

// B-fragment from swizzled LDS tile: col = fc*16 + (lane&15), k-run = (ks*4 + lane>>4)*8.
__device__ __forceinline__ bf16x8 load_bfrag(const ushort* LT, int fc, int ks, int lane) {
  int c = (fc << 4) + (lane & 15);
  int kg = (ks << 2) + (lane >> 4);
  int base = (c << 6) | (((kg ^ (c & 7) ^ ((c >> 3) & 7)) & 7) << 3);
  return *(const bf16x8*)&LT[base];
}

// One wave: C[16 x 64] = A[16 x 64] * B[64 x 64] (bf16 MFMA, fp32 acc).
__device__ __forceinline__ void mm16x64(const float* __restrict__ Arow, const ushort* LT,
                                        int lane, f32x4 acc[4]) {
#pragma unroll
  for (int ks = 0; ks < 2; ++ks) {
    bf16x8 af = load_afrag(Arow, ks, lane);
#pragma unroll
    for (int fc = 0; fc < 4; ++fc) {
      bf16x8 bf = load_bfrag(LT, fc, ks, lane);
      acc[fc] = __builtin_amdgcn_mfma_f32_16x16x32_bf16(af, bf, acc[fc], 0, 0, 0);
    }
  }
}

// ---------------------------------------------------------------------------
// K1: T1[bh][n][B][d] = sum_m L1[B][n][m] * q[b, m*64+B, h, d]   (bf16 out)
// grid (B=64, bh=64)
// ---------------------------------------------------------------------------
__global__ __launch_bounds__(256) void k_m1(const float* __restrict__ q,
                                            const float* __restrict__ L1,
                                            u16* __restrict__ T1) {
  const int B = blockIdx.x, bh = blockIdx.y;
  const int b = bh >> 3, h = bh & 7;
  __shared__ ushort LT[4096];
  const int tid = threadIdx.x, w = tid >> 6, lane = tid & 63;
  {
    const int m = tid >> 2, ch = tid & 3;
    const float* qrow = q + ((((size_t)b * S_LEN + (size_t)m * 64 + B) * 8 + h) << 6);
#pragma unroll
    for (int i = 0; i < 4; ++i) {
      float4 v = *(const float4*)(qrow + ch * 16 + i * 4);
      int c0 = ch * 16 + i * 4;
      LT[ltelem(c0 + 0, m)] = f2bf(v.x);
      LT[ltelem(c0 + 1, m)] = f2bf(v.y);
      LT[ltelem(c0 + 2, m)] = f2bf(v.z);
      LT[ltelem(c0 + 3, m)] = f2bf(v.w);
    }
  }
  __syncthreads();
  f32x4 acc[4] = {};
  mm16x64(L1 + (((size_t)B << 6) + (w << 4) + (lane & 15)) * 64, LT, lane, acc);
#pragma unroll
  for (int fc = 0; fc < 4; ++fc) {
    int d = (fc << 4) + (lane & 15);
#pragma unroll
    for (int r = 0; r < 4; ++r) {
      int n = (w << 4) + ((lane >> 4) << 2) + r;
      T1[(((size_t)bh * 64 + n) * 64 + B) * 64 + d] = f2bf(acc[fc][r]);
    }
  }
}

// ---------------------------------------------------------------------------
// K2: per (bh, n):  mm(R1) -> *k + b1 -> mm(L2) -> T2[bh][n'][n][d]
// grid (n=64, bh=64)
// ---------------------------------------------------------------------------
__global__ __launch_bounds__(256) void k_m2b(const u16* __restrict__ T1,
                                             const float* __restrict__ R1,
                                             const float* __restrict__ L2,
                                             const float* __restrict__ keys,
                                             const float* __restrict__ b1,
                                             u16* __restrict__ T2) {
  const int n = blockIdx.x, bh = blockIdx.y;
  const int b = bh >> 3, h = bh & 7;
  __shared__ ushort LT[4096];    // T1 tile, (c=d, r=B)
  __shared__ ushort LT2[4096];   // A tile,  (c=d, r=p)
  __shared__ ushort KT[4096];    // keys,    (c=d, r=p)
  const int tid = threadIdx.x, w = tid >> 6, lane = tid & 63;
  {
    const int rowi = tid >> 2, ch = tid & 3;
    const u16* src = T1 + (((size_t)bh * 64 + n) * 64 + rowi) * 64 + ch * 16;
    u16 buf[16];
    *(uint4*)&buf[0] = *(const uint4*)(src);
    *(uint4*)&buf[8] = *(const uint4*)(src + 8);
#pragma unroll
    for (int e = 0; e < 16; ++e) LT[ltelem(ch * 16 + e, rowi)] = buf[e];
  }
#pragma unroll
  for (int i = 0; i < 4; ++i) {  // stage keys rows s = p*64+n
    int idx = i * 256 + tid;
    int p = idx >> 4, c4 = (idx & 15) * 4;
    float4 kv = *(const float4*)&keys[(((size_t)b * S_LEN + p * 64 + n) * 8 + h) * 64 + c4];
    KT[ltelem(c4 + 0, p)] = f2bf(kv.x);
    KT[ltelem(c4 + 1, p)] = f2bf(kv.y);
    KT[ltelem(c4 + 2, p)] = f2bf(kv.z);
    KT[ltelem(c4 + 3, p)] = f2bf(kv.w);
  }
  __syncthreads();
  f32x4 acc[4] = {};
  mm16x64(R1 + ((size_t)n * 64 + (w << 4) + (lane & 15)) * 64, LT, lane, acc);
  float b1v[4];
#pragma unroll
  for (int r = 0; r < 4; ++r)
    b1v[r] = b1[((w << 4) + ((lane >> 4) << 2) + r) * 64 + n];
#pragma unroll
  for (int fc = 0; fc < 4; ++fc) {
    int d = (fc << 4) + (lane & 15);
#pragma unroll
    for (int r = 0; r < 4; ++r) {
      int p = (w << 4) + ((lane >> 4) << 2) + r;
      float kvv = bf2f(KT[ltelem(d, p)]);
      LT2[ltelem(d, p)] = f2bf(acc[fc][r] * kvv + b1v[r]);
    }
  }
  __syncthreads();
  f32x4 acc2[4] = {};
  mm16x64(L2 + ((size_t)n * 64 + (w << 4) + (lane & 15)) * 64, LT2, lane, acc2);
#pragma unroll
  for (int fc = 0; fc < 4; ++fc) {
    int d = (fc << 4) + (lane & 15);
#pragma unroll
    for (int r = 0; r < 4; ++r) {
      int n2 = (w << 4) + ((lane >> 4) << 2) + r;
      T2[(((size_t)bh * 64 + n2) * 64 + n) * 64 + d] = f2bf(acc2[fc][r]);
    }
  }
}

// ---------------------------------------------------------------------------
// K3: per (bh, n'): mm(R2) -> (+b2)*v -> Yp[bh][n'][p][d] bf16
// grid (n'=64, bh=64)
// ---------------------------------------------------------------------------
__global__ __launch_bounds__(256) void k_m3b(const u16* __restrict__ T2,
                                             const float* __restrict__ R2,
                                             const float* __restrict__ vals,
                                             const float* __restrict__ b2,
                                             u16* __restrict__ Yp) {
  const int np = blockIdx.x, bh = blockIdx.y;
  const int b = bh >> 3, h = bh & 7;
  __shared__ ushort LT[4096];    // T2 tile, (c=d, r=n)
  __shared__ ushort VT[4096];    // vals,    (c=d, r=p)
  const int tid = threadIdx.x, w = tid >> 6, lane = tid & 63;
  {
    const int rowi = tid >> 2, ch = tid & 3;
    const u16* src = T2 + (((size_t)bh * 64 + np) * 64 + rowi) * 64 + ch * 16;
    u16 buf[16];
    *(uint4*)&buf[0] = *(const uint4*)(src);
    *(uint4*)&buf[8] = *(const uint4*)(src + 8);
#pragma unroll
    for (int e = 0; e < 16; ++e) LT[ltelem(ch * 16 + e, rowi)] = buf[e];
  }
#pragma unroll
  for (int i = 0; i < 4; ++i) {  // stage vals rows s = p*64+np
    int idx = i * 256 + tid;
    int p = idx >> 4, c4 = (idx & 15) * 4;
    float4 vv = *(const float4*)&vals[(((size_t)b * S_LEN + p * 64 + np) * 8 + h) * 64 + c4];
    VT[ltelem(c4 + 0, p)] = f2bf(vv.x);
    VT[ltelem(c4 + 1, p)] = f2bf(vv.y);
    VT[ltelem(c4 + 2, p)] = f2bf(vv.z);
    VT[ltelem(c4 + 3, p)] = f2bf(vv.w);
  }
  __syncthreads();
  f32x4 acc[4] = {};
  mm16x64(R2 + ((size_t)np * 64 + (w << 4) + (lane & 15)) * 64, LT, lane, acc);
  float b2v[4];
#pragma unroll
  for (int r = 0; r < 4; ++r)
    b2v[r] = b2[((w << 4) + ((lane >> 4) << 2) + r) * 64 + np];
#pragma unroll
  for (int fc = 0; fc < 4; ++fc) {
    int d = (fc << 4) + (lane & 15);
#pragma unroll
    for (int r = 0; r < 4; ++r) {
      int p = (w << 4) + ((lane >> 4) << 2) + r;
      float vv = bf2f(VT[ltelem(d, p)]);
      Yp[(((size_t)bh * 64 + np) * 64 + p) * 64 + d] = f2bf((acc[fc][r] + b2v[r]) * vv);
    }
  }
}

// ---------------------------------------------------------------------------
// K4: out[bh][d][p*64+np] = Yp[bh][np][p][d]  (fp32 out, coalesced both sides)
// grid (p=64, bh=64)
// ---------------------------------------------------------------------------
__global__ __launch_bounds__(256) void k_tr(const u16* __restrict__ Yp,
                                            float* __restrict__ out) {
  const int p = blockIdx.x, bh = blockIdx.y;
  __shared__ ushort YT[4096];    // (c=np, r=d)
  const int tid = threadIdx.x;
#pragma unroll
  for (int i = 0; i < 2; ++i) {
    int idx = i * 256 + tid;
    int np = idx >> 3, q8 = idx & 7;   // d0 = q8*8
    uint4 vv = *(const uint4*)&Yp[(((size_t)bh * 64 + np) * 64 + p) * 64 + q8 * 8];
    *(uint4*)&YT[ltelem(np, q8 * 8)] = vv;
  }
  __syncthreads();
#pragma unroll
  for (int i = 0; i < 4; ++i) {
    int idx = i * 256 + tid;
    int d = idx >> 4, np0 = (idx & 15) * 4;
    float4 o;
    o.x = bf2f(YT[ltelem(np0 + 0, d)]);
    o.y = bf2f(YT[ltelem(np0 + 1, d)]);
    o.z = bf2f(YT[ltelem(np0 + 2, d)]);
    o.w = bf2f(YT[ltelem(np0 + 3, d)]);
    *(float4*)&out[((size_t)bh * 64 + d) * S_LEN + p * 64 + np0] = o;
  }
}

// ---------------------------------------------------------------------------
extern "C" void kernel_launch(void* const* d_in, const int* in_sizes, int n_in,
                              void* d_out, int out_size, void* d_ws, size_t ws_size,
                              hipStream_t stream) {
  const float* q   = (const float*)d_in[0];
  const float* k   = (const float*)d_in[1];
  const float* v   = (const float*)d_in[2];
  const float* M1L = (const float*)d_in[3];
  const float* M1R = (const float*)d_in[4];
  const float* M2L = (const float*)d_in[5];
  const float* M2R = (const float*)d_in[6];
  const float* b1  = (const float*)d_in[7];
  const float* b2  = (const float*)d_in[8];

  u16* T1 = (u16*)d_ws;
  u16* T2 = T1 + (size_t)64 * 64 * 64 * 64;  // 32 MB each
  u16* Yp = T1;                              // T1 dead after K2 — reuse

  dim3 blk(256);
  dim3 grd(64, 64);
  k_m1 <<<grd, blk, 0, stream>>>(q, M1L, T1);
  k_m2b<<<grd, blk, 0, stream>>>(T1, M1R, M2L, k, b1, T2);
  k_m3b<<<grd, blk, 0, stream>>>(T2, M2R, v, b2, Yp);
  k_tr <<<grd, blk, 0, stream>>>(Yp, (float*)d_out);
}

// Round 4
// 109.387 us; speedup vs baseline: 1.5956x; 1.0612x over previous
//
#include <hip/hip_runtime.h>
#include <cstdint>
#include <cstddef>

typedef unsigned short u16;
typedef __attribute__((ext_vector_type(8))) short bf16x8;
typedef __attribute__((ext_vector_type(4))) float f32x4;

#define S_LEN 4096

__device__ __forceinline__ float bf2f(u16 u) {
  return __uint_as_float(((unsigned)u) << 16);
}
__device__ __forceinline__ u16 f2bf(float f) {
  unsigned x = __float_as_uint(f);
  return (u16)((x + 0x7fffu + ((x >> 16) & 1u)) >> 16);
}

// XOR-swizzled 64x64 u16 LDS tile: logical (c=col, r=row), row = contraction.
__device__ __forceinline__ int ltelem(int c, int r) {
  int swz = ((r >> 3) ^ (c & 7) ^ ((c >> 3) & 7)) & 7;
  return (c << 6) | (swz << 3) | (r & 7);
}

// B-fragment from swizzled LDS: col = fc*16 + (lane&15), k-run = (ks*4 + lane>>4)*8.
__device__ __forceinline__ bf16x8 load_bfrag(const ushort* LT, int fc, int ks, int lane) {
  int c = (fc << 4) + (lane & 15);
  int kg = (ks << 2) + (lane >> 4);
  int base = (c << 6) | (((kg ^ (c & 7) ^ ((c >> 3) & 7)) & 7) << 3);
  return *(const bf16x8*)&LT[base];
}

// A-fragment from pre-packed bf16 weights.
// APK[mat][gr][ks][lane][8]  with  row = gr*16 + (lane&15), k = ks*32 + (lane>>4)*8 + e.
__device__ __forceinline__ bf16x8 apk_frag(const u16* __restrict__ APK, int mat, int gr,
                                           int ks, int lane) {
  return *(const bf16x8*)&APK[(((((mat << 8) + gr) << 1) + ks) << 9) + lane * 8];
}

// One wave: C[16 rows x 64 cols] = A[16 x 64] * B[64 x 64] (bf16 MFMA, fp32 acc).
__device__ __forceinline__ void mm16x64(const u16* __restrict__ APK, int mat, int gr,
                                        const ushort* LT, int lane, f32x4 acc[4]) {
#pragma unroll
  for (int ks = 0; ks < 2; ++ks) {
    bf16x8 af = apk_frag(APK, mat, gr, ks, lane);
#pragma unroll
    for (int fc = 0; fc < 4; ++fc) {
      bf16x8 bf = load_bfrag(LT, fc, ks, lane);
      acc[fc] = __builtin_amdgcn_mfma_f32_16x16x32_bf16(af, bf, acc[fc], 0, 0, 0);
    }
  }
}

// ---------------------------------------------------------------------------
// k_prep: pack {M1L,M1R,M2L,M2R} (fp32 64^3 row-major) into A-fragment order bf16.
// grid (gr=256, mat=4), 256 thr.
// ---------------------------------------------------------------------------
__global__ __launch_bounds__(256) void k_prep(const float* __restrict__ W0,
                                              const float* __restrict__ W1,
                                              const float* __restrict__ W2,
                                              const float* __restrict__ W3,
                                              u16* __restrict__ APK) {
  const int gr = blockIdx.x, mat = blockIdx.y;
  const float* W = (mat == 0) ? W0 : (mat == 1) ? W1 : (mat == 2) ? W2 : W3;
  const int t = threadIdx.x;
  const int lane = t & 63, ks = (t >> 6) & 1, half = t >> 7;
  const int row = gr * 16 + (lane & 15);
  const int k0 = ks * 32 + ((lane >> 4) << 3) + half * 4;
  float4 v = *(const float4*)&W[row * 64 + k0];
  ushort4 o;
  o.x = f2bf(v.x); o.y = f2bf(v.y); o.z = f2bf(v.z); o.w = f2bf(v.w);
  *(ushort4*)&APK[((((((mat << 8) + gr) << 1) + ks) << 6) + lane) * 8 + half * 4] = o;
}

// ---------------------------------------------------------------------------
// K1: T1[bh][n][B][d] = sum_m L1[B][n][m] * q[b, m*64+B, h, d]   (bf16 out)
// grid (B=64, bh=64)
// ---------------------------------------------------------------------------
__global__ __launch_bounds__(256) void k_m1(const float* __restrict__ q,
                                            const u16* __restrict__ APK,
                                            u16* __restrict__ T1) {
  const int B = blockIdx.x, bh = blockIdx.y;
  const int b = bh >> 3, h = bh & 7;
  __shared__ ushort LT[4096];
  const int tid = threadIdx.x, w = tid >> 6, lane = tid & 63;
  {
    const int m = tid >> 2, ch = tid & 3;
    const float* qrow = q + ((((size_t)b * S_LEN + (size_t)m * 64 + B) * 8 + h) << 6);
#pragma unroll
    for (int i = 0; i < 4; ++i) {
      float4 v = *(const float4*)(qrow + ch * 16 + i * 4);
      int c0 = ch * 16 + i * 4;
      LT[ltelem(c0 + 0, m)] = f2bf(v.x);
      LT[ltelem(c0 + 1, m)] = f2bf(v.y);
      LT[ltelem(c0 + 2, m)] = f2bf(v.z);
      LT[ltelem(c0 + 3, m)] = f2bf(v.w);
    }
  }
  __syncthreads();
  f32x4 acc[4] = {};
  mm16x64(APK, 0, B * 4 + w, LT, lane, acc);
#pragma unroll
  for (int fc = 0; fc < 4; ++fc) {
    int d = (fc << 4) + (lane & 15);
#pragma unroll
    for (int r = 0; r < 4; ++r) {
      int n = (w << 4) + ((lane >> 4) << 2) + r;
      T1[(((size_t)bh * 64 + n) * 64 + B) * 64 + d] = f2bf(acc[fc][r]);
    }
  }
}

// ---------------------------------------------------------------------------
// K2: per (bh, n):  mm(R1) -> *k + b1 -> mm(L2) -> T2[bh][n'][n][d]
// grid (n=64, bh=64).  keys loaded straight to registers (issue-early).
// ---------------------------------------------------------------------------
__global__ __launch_bounds__(256) void k_m2b(const u16* __restrict__ T1,
                                             const u16* __restrict__ APK,
                                             const float* __restrict__ keys,
                                             const float* __restrict__ b1,
                                             u16* __restrict__ T2) {
  const int n = blockIdx.x, bh = blockIdx.y;
  const int b = bh >> 3, h = bh & 7;
  __shared__ ushort LT[4096];    // T1 tile, (c=d, r=B)
  __shared__ ushort LT2[4096];   // A tile,  (c=d, r=p)
  const int tid = threadIdx.x, w = tid >> 6, lane = tid & 63;

  // issue-early: keys values at this thread's C-fragment positions + b1.
  float kreg[4][4], b1v[4];
#pragma unroll
  for (int r = 0; r < 4; ++r) {
    int p = (w << 4) + ((lane >> 4) << 2) + r;
    b1v[r] = b1[p * 64 + n];
    const float* krow = &keys[(((size_t)b * S_LEN + p * 64 + n) * 8 + h) << 6];
#pragma unroll
    for (int fc = 0; fc < 4; ++fc)
      kreg[fc][r] = krow[(fc << 4) + (lane & 15)];
  }
  {
    const int rowi = tid >> 2, ch = tid & 3;
    const u16* src = T1 + (((size_t)bh * 64 + n) * 64 + rowi) * 64 + ch * 16;
    u16 buf[16];
    *(uint4*)&buf[0] = *(const uint4*)(src);
    *(uint4*)&buf[8] = *(const uint4*)(src + 8);
#pragma unroll
    for (int e = 0; e < 16; ++e) LT[ltelem(ch * 16 + e, rowi)] = buf[e];
  }
  __syncthreads();
  f32x4 acc[4] = {};
  mm16x64(APK, 1, n * 4 + w, LT, lane, acc);   // R1
#pragma unroll
  for (int fc = 0; fc < 4; ++fc) {
    int d = (fc << 4) + (lane & 15);
#pragma unroll
    for (int r = 0; r < 4; ++r) {
      int p = (w << 4) + ((lane >> 4) << 2) + r;
      LT2[ltelem(d, p)] = f2bf(acc[fc][r] * kreg[fc][r] + b1v[r]);
    }
  }
  __syncthreads();
  f32x4 acc2[4] = {};
  mm16x64(APK, 2, n * 4 + w, LT2, lane, acc2);  // L2
#pragma unroll
  for (int fc = 0; fc < 4; ++fc) {
    int d = (fc << 4) + (lane & 15);
#pragma unroll
    for (int r = 0; r < 4; ++r) {
      int n2 = (w << 4) + ((lane >> 4) << 2) + r;
      T2[(((size_t)bh * 64 + n2) * 64 + n) * 64 + d] = f2bf(acc2[fc][r]);
    }
  }
}

// ---------------------------------------------------------------------------
// K3: per (bh, n'): mm(R2) -> (+b2)*v -> Yp[bh][n'][p][d] bf16
// grid (n'=64, bh=64).  vals loaded straight to registers (issue-early).
// ---------------------------------------------------------------------------
__global__ __launch_bounds__(256) void k_m3b(const u16* __restrict__ T2,
                                             const u16* __restrict__ APK,
                                             const float* __restrict__ vals,
                                             const float* __restrict__ b2,
                                             u16* __restrict__ Yp) {
  const int np = blockIdx.x, bh = blockIdx.y;
  const int b = bh >> 3, h = bh & 7;
  __shared__ ushort LT[4096];    // T2 tile, (c=d, r=n)
  const int tid = threadIdx.x, w = tid >> 6, lane = tid & 63;

  float vreg[4][4], b2v[4];
#pragma unroll
  for (int r = 0; r < 4; ++r) {
    int p = (w << 4) + ((lane >> 4) << 2) + r;
    b2v[r] = b2[p * 64 + np];
    const float* vrow = &vals[(((size_t)b * S_LEN + p * 64 + np) * 8 + h) << 6];
#pragma unroll
    for (int fc = 0; fc < 4; ++fc)
      vreg[fc][r] = vrow[(fc << 4) + (lane & 15)];
  }
  {
    const int rowi = tid >> 2, ch = tid & 3;
    const u16* src = T2 + (((size_t)bh * 64 + np) * 64 + rowi) * 64 + ch * 16;
    u16 buf[16];
    *(uint4*)&buf[0] = *(const uint4*)(src);
    *(uint4*)&buf[8] = *(const uint4*)(src + 8);
#pragma unroll
    for (int e = 0; e < 16; ++e) LT[ltelem(ch * 16 + e, rowi)] = buf[e];
  }
  __syncthreads();
  f32x4 acc[4] = {};
  mm16x64(APK, 3, np * 4 + w, LT, lane, acc);   // R2
#pragma unroll
  for (int fc = 0; fc < 4; ++fc) {
    int d = (fc << 4) + (lane & 15);
#pragma unroll
    for (int r = 0; r < 4; ++r) {
      int p = (w << 4) + ((lane >> 4) << 2) + r;
      Yp[(((size_t)bh * 64 + np) * 64 + p) * 64 + d] = f2bf((acc[fc][r] + b2v[r]) * vreg[fc][r]);
    }
  }
}

// ---------------------------------------------------------------------------
// K4: out[bh][d][p*64+np] = Yp[bh][np][p][d]  (fp32, coalesced both sides)
// grid (p=64, bh=64)
// ---------------------------------------------------------------------------
__global__ __launch_bounds__(256) void k_tr(const u16* __restrict__ Yp,
                                            float* __restrict__ out) {
  const int p = blockIdx.x, bh = blockIdx.y;
  __shared__ ushort YT[4096];    // (c=np, r=d)
  const int tid = threadIdx.x;
#pragma unroll
  for (int i = 0; i < 2; ++i) {
    int idx = i * 256 + tid;
    int np = idx >> 3, q8 = idx & 7;   // d0 = q8*8
    uint4 vv = *(const uint4*)&Yp[(((size_t)bh * 64 + np) * 64 + p) * 64 + q8 * 8];
    *(uint4*)&YT[ltelem(np, q8 * 8)] = vv;
  }
  __syncthreads();
#pragma unroll
  for (int i = 0; i < 4; ++i) {
    int idx = i * 256 + tid;
    int d = idx >> 4, np0 = (idx & 15) * 4;
    float4 o;
    o.x = bf2f(YT[ltelem(np0 + 0, d)]);
    o.y = bf2f(YT[ltelem(np0 + 1, d)]);
    o.z = bf2f(YT[ltelem(np0 + 2, d)]);
    o.w = bf2f(YT[ltelem(np0 + 3, d)]);
    *(float4*)&out[((size_t)bh * 64 + d) * S_LEN + p * 64 + np0] = o;
  }
}

// ---------------------------------------------------------------------------
extern "C" void kernel_launch(void* const* d_in, const int* in_sizes, int n_in,
                              void* d_out, int out_size, void* d_ws, size_t ws_size,
                              hipStream_t stream) {
  const float* q   = (const float*)d_in[0];
  const float* k   = (const float*)d_in[1];
  const float* v   = (const float*)d_in[2];
  const float* M1L = (const float*)d_in[3];
  const float* M1R = (const float*)d_in[4];
  const float* M2L = (const float*)d_in[5];
  const float* M2R = (const float*)d_in[6];
  const float* b1  = (const float*)d_in[7];
  const float* b2  = (const float*)d_in[8];

  u16* T1 = (u16*)d_ws;
  u16* T2 = T1 + (size_t)64 * 64 * 64 * 64;  // 32 MB each
  u16* Yp = T1;                              // T1 dead after K2 — reuse
  // Apack (2 MB) lives in the head of d_out: consumed by k_m1..k_m3b, then k_tr
  // (the final kernel) overwrites every output element. d_out is 64 MiB.
  u16* APK = (u16*)d_out;

  dim3 blk(256);
  dim3 grd(64, 64);
  k_prep<<<dim3(256, 4), blk, 0, stream>>>(M1L, M1R, M2L, M2R, APK);
  k_m1 <<<grd, blk, 0, stream>>>(q, APK, T1);
  k_m2b<<<grd, blk, 0, stream>>>(T1, APK, k, b1, T2);
  k_m3b<<<grd, blk, 0, stream>>>(T2, APK, v, b2, Yp);
  k_tr <<<grd, blk, 0, stream>>>(Yp, (float*)d_out);
}

// Round 5
// 108.606 us; speedup vs baseline: 1.6070x; 1.0072x over previous
//
#include <hip/hip_runtime.h>
#include <cstdint>
#include <cstddef>

typedef unsigned short u16;
typedef __attribute__((ext_vector_type(8))) short bf16x8;
typedef __attribute__((ext_vector_type(4))) float f32x4;

#define S_LEN 4096

__device__ __forceinline__ float bf2f(u16 u) {
  return __uint_as_float(((unsigned)u) << 16);
}
__device__ __forceinline__ u16 f2bf(float f) {
  unsigned x = __float_as_uint(f);
  return (u16)((x + 0x7fffu + ((x >> 16) & 1u)) >> 16);
}

// XOR-swizzled 64x64 u16 LDS tile: logical (c=col, r=row), row = contraction.
__device__ __forceinline__ int ltelem(int c, int r) {
  int swz = ((r >> 3) ^ (c & 7) ^ ((c >> 3) & 7)) & 7;
  return (c << 6) | (swz << 3) | (r & 7);
}

// Tile fragment (used as MFMA *A* operand): row = a*16 + (lane&15) over tile
// column dim c, k-run = (ks*4 + lane>>4)*8 over tile row dim r.
__device__ __forceinline__ bf16x8 tile_frag(const ushort* LT, int a, int ks, int lane) {
  int c = (a << 4) + (lane & 15);
  int kg = (ks << 2) + (lane >> 4);
  int base = (c << 6) | (((kg ^ (c & 7) ^ ((c >> 3) & 7)) & 7) << 3);
  return *(const bf16x8*)&LT[base];
}

// Pre-packed bf16 weight fragment (used as MFMA *B* operand):
// col = gr*16 + (lane&15) (flat weight row), k = ks*32 + (lane>>4)*8 + e.
__device__ __forceinline__ bf16x8 apk_frag(const u16* __restrict__ APK, int mat, int gr,
                                           int ks, int lane) {
  return *(const bf16x8*)&APK[(((((mat << 8) + gr) << 1) + ks) << 9) + lane * 8];
}

// One wave: C[d=64 rows][16 cols] = Tile^T[64x64] * W^T — transposed orientation.
// acc[a]: rows d = a*16 + (lane>>4)*4 + reg (4 CONSECUTIVE d per lane),
//         col  = gr*16 + (lane&15).
__device__ __forceinline__ void mmT(const ushort* LT, const u16* __restrict__ APK,
                                    int mat, int gr, int lane, f32x4 acc[4]) {
#pragma unroll
  for (int ks = 0; ks < 2; ++ks) {
    bf16x8 bw = apk_frag(APK, mat, gr, ks, lane);
#pragma unroll
    for (int a = 0; a < 4; ++a) {
      bf16x8 at = tile_frag(LT, a, ks, lane);
      acc[a] = __builtin_amdgcn_mfma_f32_16x16x32_bf16(at, bw, acc[a], 0, 0, 0);
    }
  }
}

// ---------------------------------------------------------------------------
// k_prep: pack {M1L,M1R,M2L,M2R} (fp32 64^3 row-major) into fragment order bf16.
// grid (gr=256, mat=4), 256 thr.
// ---------------------------------------------------------------------------
__global__ __launch_bounds__(256) void k_prep(const float* __restrict__ W0,
                                              const float* __restrict__ W1,
                                              const float* __restrict__ W2,
                                              const float* __restrict__ W3,
                                              u16* __restrict__ APK) {
  const int gr = blockIdx.x, mat = blockIdx.y;
  const float* W = (mat == 0) ? W0 : (mat == 1) ? W1 : (mat == 2) ? W2 : W3;
  const int t = threadIdx.x;
  const int lane = t & 63, ks = (t >> 6) & 1, half = t >> 7;
  const int row = gr * 16 + (lane & 15);
  const int k0 = ks * 32 + ((lane >> 4) << 3) + half * 4;
  float4 v = *(const float4*)&W[row * 64 + k0];
  ushort4 o;
  o.x = f2bf(v.x); o.y = f2bf(v.y); o.z = f2bf(v.z); o.w = f2bf(v.w);
  *(ushort4*)&APK[((((((mat << 8) + gr) << 1) + ks) << 6) + lane) * 8 + half * 4] = o;
}

// ---------------------------------------------------------------------------
// K1: T1[bh][n][B][d] = sum_m L1[B][n][m] * q[b, m*64+B, h, d]   (bf16 out)
// grid (B=64, bh=64)
// ---------------------------------------------------------------------------
__global__ __launch_bounds__(256) void k_m1(const float* __restrict__ q,
                                            const u16* __restrict__ APK,
                                            u16* __restrict__ T1) {
  const int B = blockIdx.x, bh = blockIdx.y;
  const int b = bh >> 3, h = bh & 7;
  __shared__ ushort LT[4096];          // (c=d, r=m)
  const int tid = threadIdx.x, w = tid >> 6, lane = tid & 63;
  {
    const int m = tid >> 2, ch = tid & 3;
    const float* qrow = q + ((((size_t)b * S_LEN + (size_t)m * 64 + B) * 8 + h) << 6);
#pragma unroll
    for (int i = 0; i < 4; ++i) {
      float4 v = *(const float4*)(qrow + ch * 16 + i * 4);
      int c0 = ch * 16 + i * 4;
      LT[ltelem(c0 + 0, m)] = f2bf(v.x);
      LT[ltelem(c0 + 1, m)] = f2bf(v.y);
      LT[ltelem(c0 + 2, m)] = f2bf(v.z);
      LT[ltelem(c0 + 3, m)] = f2bf(v.w);
    }
  }
  __syncthreads();
  f32x4 acc[4] = {};
  mmT(LT, APK, 0, B * 4 + w, lane, acc);        // C[d][n]
  const int n = (w << 4) + (lane & 15);
  const int dg = (lane >> 4) << 2;
#pragma unroll
  for (int a = 0; a < 4; ++a) {
    int d0 = (a << 4) + dg;
    ushort4 o;
    o.x = f2bf(acc[a][0]); o.y = f2bf(acc[a][1]);
    o.z = f2bf(acc[a][2]); o.w = f2bf(acc[a][3]);
    *(ushort4*)&T1[(((size_t)bh * 64 + n) * 64 + B) * 64 + d0] = o;
  }
}

// ---------------------------------------------------------------------------
// K2: per (bh, n):  mm(R1) -> *k + b1 -> mm(L2) -> T2[bh][n'][n][d]
// grid (n=64, bh=64).  keys via 4 float4 register loads (issue-early).
// ---------------------------------------------------------------------------
__global__ __launch_bounds__(256) void k_m2b(const u16* __restrict__ T1,
                                             const u16* __restrict__ APK,
                                             const float* __restrict__ keys,
                                             const float* __restrict__ b1,
                                             u16* __restrict__ T2) {
  const int n = blockIdx.x, bh = blockIdx.y;
  const int b = bh >> 3, h = bh & 7;
  __shared__ ushort LT[4096];    // T1 tile, (c=d, r=B)
  __shared__ ushort LT2[4096];   // A tile,  (c=d, r=p)
  const int tid = threadIdx.x, w = tid >> 6, lane = tid & 63;
  const int p = (w << 4) + (lane & 15);
  const int dg = (lane >> 4) << 2;

  // issue-early: this lane's keys row chunks + bias.
  const float b1v = b1[p * 64 + n];
  const float* krow = &keys[(((size_t)b * S_LEN + p * 64 + n) * 8 + h) << 6];
  float4 kreg[4];
#pragma unroll
  for (int a = 0; a < 4; ++a) kreg[a] = *(const float4*)(krow + (a << 4) + dg);

  {
    const int rowi = tid >> 2, ch = tid & 3;
    const u16* src = T1 + (((size_t)bh * 64 + n) * 64 + rowi) * 64 + ch * 16;
    u16 buf[16];
    *(uint4*)&buf[0] = *(const uint4*)(src);
    *(uint4*)&buf[8] = *(const uint4*)(src + 8);
#pragma unroll
    for (int e = 0; e < 16; ++e) LT[ltelem(ch * 16 + e, rowi)] = buf[e];
  }
  __syncthreads();
  f32x4 acc[4] = {};
  mmT(LT, APK, 1, n * 4 + w, lane, acc);        // C[d][p]
#pragma unroll
  for (int a = 0; a < 4; ++a) {
    int d0 = (a << 4) + dg;
    LT2[ltelem(d0 + 0, p)] = f2bf(acc[a][0] * kreg[a].x + b1v);
    LT2[ltelem(d0 + 1, p)] = f2bf(acc[a][1] * kreg[a].y + b1v);
    LT2[ltelem(d0 + 2, p)] = f2bf(acc[a][2] * kreg[a].z + b1v);
    LT2[ltelem(d0 + 3, p)] = f2bf(acc[a][3] * kreg[a].w + b1v);
  }
  __syncthreads();
  f32x4 acc2[4] = {};
  mmT(LT2, APK, 2, n * 4 + w, lane, acc2);      // C[d][n2]
  const int n2 = (w << 4) + (lane & 15);
#pragma unroll
  for (int a = 0; a < 4; ++a) {
    int d0 = (a << 4) + dg;
    ushort4 o;
    o.x = f2bf(acc2[a][0]); o.y = f2bf(acc2[a][1]);
    o.z = f2bf(acc2[a][2]); o.w = f2bf(acc2[a][3]);
    *(ushort4*)&T2[(((size_t)bh * 64 + n2) * 64 + n) * 64 + d0] = o;
  }
}

// ---------------------------------------------------------------------------
// K3: per (bh, n'): mm(R2) -> (+b2)*v -> Yp[bh][n'][p][d] bf16
// grid (n'=64, bh=64).  vals via 4 float4 register loads (issue-early).
// ---------------------------------------------------------------------------
__global__ __launch_bounds__(256) void k_m3b(const u16* __restrict__ T2,
                                             const u16* __restrict__ APK,
                                             const float* __restrict__ vals,
                                             const float* __restrict__ b2,
                                             u16* __restrict__ Yp) {
  const int np = blockIdx.x, bh = blockIdx.y;
  const int b = bh >> 3, h = bh & 7;
  __shared__ ushort LT[4096];    // T2 tile, (c=d, r=n)
  const int tid = threadIdx.x, w = tid >> 6, lane = tid & 63;
  const int p = (w << 4) + (lane & 15);
  const int dg = (lane >> 4) << 2;

  const float b2v = b2[p * 64 + np];
  const float* vrow = &vals[(((size_t)b * S_LEN + p * 64 + np) * 8 + h) << 6];
  float4 vreg[4];
#pragma unroll
  for (int a = 0; a < 4; ++a) vreg[a] = *(const float4*)(vrow + (a << 4) + dg);

  {
    const int rowi = tid >> 2, ch = tid & 3;
    const u16* src = T2 + (((size_t)bh * 64 + np) * 64 + rowi) * 64 + ch * 16;
    u16 buf[16];
    *(uint4*)&buf[0] = *(const uint4*)(src);
    *(uint4*)&buf[8] = *(const uint4*)(src + 8);
#pragma unroll
    for (int e = 0; e < 16; ++e) LT[ltelem(ch * 16 + e, rowi)] = buf[e];
  }
  __syncthreads();
  f32x4 acc[4] = {};
  mmT(LT, APK, 3, np * 4 + w, lane, acc);       // C[d][p']
#pragma unroll
  for (int a = 0; a < 4; ++a) {
    int d0 = (a << 4) + dg;
    ushort4 o;
    o.x = f2bf((acc[a][0] + b2v) * vreg[a].x);
    o.y = f2bf((acc[a][1] + b2v) * vreg[a].y);
    o.z = f2bf((acc[a][2] + b2v) * vreg[a].z);
    o.w = f2bf((acc[a][3] + b2v) * vreg[a].w);
    *(ushort4*)&Yp[(((size_t)bh * 64 + np) * 64 + p) * 64 + d0] = o;
  }
}

// ---------------------------------------------------------------------------
// K4: out[bh][d][p*64+np] = Yp[bh][np][p][d]  (fp32, coalesced both sides)
// grid (p=64, bh=64)
// ---------------------------------------------------------------------------
__global__ __launch_bounds__(256) void k_tr(const u16* __restrict__ Yp,
                                            float* __restrict__ out) {
  const int p = blockIdx.x, bh = blockIdx.y;
  __shared__ ushort YT[4096];    // (c=np, r=d)
  const int tid = threadIdx.x;
#pragma unroll
  for (int i = 0; i < 2; ++i) {
    int idx = i * 256 + tid;
    int np = idx >> 3, q8 = idx & 7;   // d0 = q8*8
    uint4 vv = *(const uint4*)&Yp[(((size_t)bh * 64 + np) * 64 + p) * 64 + q8 * 8];
    *(uint4*)&YT[ltelem(np, q8 * 8)] = vv;
  }
  __syncthreads();
#pragma unroll
  for (int i = 0; i < 4; ++i) {
    int idx = i * 256 + tid;
    int d = idx >> 4, np0 = (idx & 15) * 4;
    float4 o;
    o.x = bf2f(YT[ltelem(np0 + 0, d)]);
    o.y = bf2f(YT[ltelem(np0 + 1, d)]);
    o.z = bf2f(YT[ltelem(np0 + 2, d)]);
    o.w = bf2f(YT[ltelem(np0 + 3, d)]);
    *(float4*)&out[((size_t)bh * 64 + d) * S_LEN + p * 64 + np0] = o;
  }
}

// ---------------------------------------------------------------------------
extern "C" void kernel_launch(void* const* d_in, const int* in_sizes, int n_in,
                              void* d_out, int out_size, void* d_ws, size_t ws_size,
                              hipStream_t stream) {
  const float* q   = (const float*)d_in[0];
  const float* k   = (const float*)d_in[1];
  const float* v   = (const float*)d_in[2];
  const float* M1L = (const float*)d_in[3];
  const float* M1R = (const float*)d_in[4];
  const float* M2L = (const float*)d_in[5];
  const float* M2R = (const float*)d_in[6];
  const float* b1  = (const float*)d_in[7];
  const float* b2  = (const float*)d_in[8];

  u16* T1 = (u16*)d_ws;
  u16* T2 = T1 + (size_t)64 * 64 * 64 * 64;  // 32 MB each
  u16* Yp = T1;                              // T1 dead after K2 — reuse
  // Apack (2 MB) in the head of d_out: consumed by k_m1..k_m3b, then k_tr
  // (the final kernel) rewrites every output element. d_out is 64 MiB.
  u16* APK = (u16*)d_out;

  dim3 blk(256);
  dim3 grd(64, 64);
  k_prep<<<dim3(256, 4), blk, 0, stream>>>(M1L, M1R, M2L, M2R, APK);
  k_m1 <<<grd, blk, 0, stream>>>(q, APK, T1);
  k_m2b<<<grd, blk, 0, stream>>>(T1, APK, k, b1, T2);
  k_m3b<<<grd, blk, 0, stream>>>(T2, APK, v, b2, Yp);
  k_tr <<<grd, blk, 0, stream>>>(Yp, (float*)d_out);
}